// Round 7
// baseline (152.098 us; speedup 1.0000x reference)
//
#include <hip/hip_runtime.h>
#include <stdint.h>

#define NB 2
#define NS 2048
#define ND 1024
#define NH 16
#define NDK 64

typedef __attribute__((ext_vector_type(8))) short s8v;
typedef __attribute__((ext_vector_type(4))) float f4v;
typedef __attribute__((ext_vector_type(4))) unsigned short us4v;
typedef __attribute__((ext_vector_type(8))) unsigned short us8v;
typedef __attribute__((ext_vector_type(2))) uint32_t u2v;

__device__ __forceinline__ unsigned short f2bf(float f) {
  uint32_t u = __builtin_bit_cast(uint32_t, f);
  u = (u + 0x7fffu + ((u >> 16) & 1u)) >> 16;
  return (unsigned short)u;
}
__device__ __forceinline__ float bf2f(unsigned short h) {
  uint32_t u = ((uint32_t)h) << 16;
  return __builtin_bit_cast(float, u);
}
// packed f32x2 -> bf16x2 (lo -> bits[15:0]), RNE
__device__ __forceinline__ uint32_t cvtpk(float lo, float hi) {
  uint32_t r;
  asm("v_cvt_pk_bf16_f32 %0, %1, %2" : "=v"(r) : "v"(lo), "v"(hi));
  return r;
}

__device__ __forceinline__ void gload16(const void* g, void* l) {
  __builtin_amdgcn_global_load_lds(
      (const __attribute__((address_space(1))) void*)g,
      (__attribute__((address_space(3))) void*)l, 16, 0, 0);
}

// ---------------------------------------------------------------- convert x
__global__ void k_convert_x(const float* __restrict__ x, unsigned short* __restrict__ xbf) {
  int i = (blockIdx.x * 256 + threadIdx.x) * 4;
  float4 v = *(const float4*)(x + i);
  us4v o;
  o[0] = f2bf(v.x); o[1] = f2bf(v.y); o[2] = f2bf(v.z); o[3] = f2bf(v.w);
  *(us4v*)(xbf + i) = o;
}

// ------------------------------------------------- transpose+convert weights
__global__ void k_transpose_w(const float* __restrict__ Wq, const float* __restrict__ Wk,
                              const float* __restrict__ Wv, const float* __restrict__ Wo,
                              unsigned short* __restrict__ wt_qkv, unsigned short* __restrict__ wt_o) {
  __shared__ float tls[64][65];
  int bid = blockIdx.x;
  int mat = bid >> 8;
  int tile = bid & 255;
  int tk = tile >> 4, tn = tile & 15;
  const float* W = (mat == 0) ? Wq : (mat == 1) ? Wk : (mat == 2) ? Wv : Wo;
  int t = threadIdx.x;
  int lr = t >> 2;
  int lc0 = (t & 3) * 16;
  const float* src = W + (size_t)(tk * 64 + lr) * 1024 + tn * 64 + lc0;
#pragma unroll
  for (int j = 0; j < 16; j += 4) {
    float4 v = *(const float4*)(src + j);
    tls[lr][lc0 + j + 0] = v.x; tls[lr][lc0 + j + 1] = v.y;
    tls[lr][lc0 + j + 2] = v.z; tls[lr][lc0 + j + 3] = v.w;
  }
  __syncthreads();
  float scale = (mat == 0) ? 0.125f : 1.0f;
  int nr = t >> 2, kc0 = (t & 3) * 16;
  unsigned short* dst = ((mat < 3) ? (wt_qkv + (size_t)(mat * 1024 + tn * 64 + nr) * 1024)
                                   : (wt_o + (size_t)(tn * 64 + nr) * 1024)) + tk * 64 + kc0;
  us8v o0, o1;
#pragma unroll
  for (int j = 0; j < 8; j++) o0[j] = f2bf(tls[kc0 + j][nr] * scale);
#pragma unroll
  for (int j = 0; j < 8; j++) o1[j] = f2bf(tls[kc0 + 8 + j][nr] * scale);
  *(us8v*)(dst) = o0;
  *(us8v*)(dst + 8) = o1;
}

// ----------------------------------------------------------------- bf16 GEMM
// Depth-2 counted-vmcnt pipeline (T4): 3 LDS buffer stages (96 KB), STAGE(kt+2)
// issued while computing kt; pre-barrier wait is vmcnt(8) (loads for kt+2 stay
// in flight across the barrier) -- never drains to 0 in the main loop.  Raw
// s_barrier + sched_barrier(0) (no implicit vmcnt(0) drain of __syncthreads).
// Hiding window = ~2 iterations, so 1 WG/CU occupancy suffices by design.
// XCD chunking: m = 4*xcd + local%4, n-major within chunk => concurrent
// working set ~3MB < 4MB L2.
template <int MODE>
__global__ __launch_bounds__(256) void k_gemm(const unsigned short* __restrict__ A,
                                              const unsigned short* __restrict__ Bt,
                                              unsigned short* __restrict__ qklin,
                                              unsigned short* __restrict__ vt,
                                              const float* __restrict__ bias,
                                              float* __restrict__ out, int ntx) {
  __shared__ unsigned short lds_a[3][128 * 64];
  __shared__ unsigned short lds_b[3][128 * 64];
  const int K = 1024;
  const int NT = K / 64;
  int bid = blockIdx.x;
  int x = bid & 7, local = bid >> 3;
  int m0 = (x * 4 + (local & 3)) * 128;
  int n0 = (local >> 2) * 128;
  int tid = threadIdx.x, lane = tid & 63, w = tid >> 6;
  int wm = w >> 1, wn = w & 1;
  int g = lane >> 4, c0 = lane & 15;
  int rrel = lane >> 3;
  int gran = lane & 7;
  f4v acc[4][4];
#pragma unroll
  for (int mi = 0; mi < 4; mi++)
#pragma unroll
    for (int ni = 0; ni < 4; ni++) acc[mi][ni] = (f4v){0.f, 0.f, 0.f, 0.f};

#define STAGE(kt_, buf_)                                                        \
  do {                                                                          \
    int koff = (kt_)*64;                                                        \
    _Pragma("unroll") for (int i = 0; i < 4; i++) {                             \
      int r = 32 * w + 8 * i + rrel;                                            \
      gload16(A + (size_t)(m0 + r) * K + koff + 8 * (gran ^ rrel),              \
              (void*)(lds_a[buf_] + (32 * w + 8 * i) * 64));                    \
      gload16(Bt + (size_t)(n0 + r) * K + koff + 8 * (gran ^ rrel),             \
              (void*)(lds_b[buf_] + (32 * w + 8 * i) * 64));                    \
    }                                                                           \
  } while (0)

  // prologue: 2 tiles in flight; wait only for tile 0
  STAGE(0, 0);
  STAGE(1, 1);
  asm volatile("s_waitcnt vmcnt(8)" ::: "memory");
  __builtin_amdgcn_s_barrier();
  __builtin_amdgcn_sched_barrier(0);

  for (int kt = 0; kt < NT; ++kt) {
    int cur = kt % 3;
    if (kt + 2 < NT) STAGE(kt + 2, (kt + 2) % 3);
    // ---- compute from buf[cur]
#pragma unroll
    for (int c = 0; c < 2; c++) {
      s8v af[4], bfr[4];
#pragma unroll
      for (int mi = 0; mi < 4; mi++) {
        int row = 64 * wm + 16 * mi + c0;
        af[mi] = *(const s8v*)(lds_a[cur] + row * 64 + 8 * ((g + 4 * c) ^ (c0 & 7)));
      }
#pragma unroll
      for (int ni = 0; ni < 4; ni++) {
        int row = 64 * wn + 16 * ni + c0;
        bfr[ni] = *(const s8v*)(lds_b[cur] + row * 64 + 8 * ((g + 4 * c) ^ (c0 & 7)));
      }
#pragma unroll
      for (int mi = 0; mi < 4; mi++)
#pragma unroll
        for (int ni = 0; ni < 4; ni++)
          acc[mi][ni] = __builtin_amdgcn_mfma_f32_16x16x32_bf16(af[mi], bfr[ni], acc[mi][ni], 0, 0, 0);
    }
    if (kt + 1 < NT) {
      // need S(kt+1) complete; S(kt+2) (8 loads) may stay in flight
      if (kt + 2 < NT) {
        asm volatile("s_waitcnt vmcnt(8)" ::: "memory");
      } else {
        asm volatile("s_waitcnt vmcnt(0)" ::: "memory");
      }
      __builtin_amdgcn_s_barrier();
      __builtin_amdgcn_sched_barrier(0);
    }
  }
#undef STAGE

#pragma unroll
  for (int mi = 0; mi < 4; mi++)
#pragma unroll
    for (int ni = 0; ni < 4; ni++)
#pragma unroll
      for (int r = 0; r < 4; r++) {
        int m = m0 + 64 * wm + 16 * mi + 4 * g + r;
        int n = n0 + 64 * wn + 16 * ni + c0;
        float v = acc[mi][ni][r];
        if (MODE == 0) {
          unsigned short hv = f2bf(v);
          if (n < 2048) {
            qklin[(size_t)m * 2048 + n] = hv;
          } else {
            int b = m >> 11, s = m & 2047;
            int hh = (n - 2048) >> 6, dk = n & 63;
            vt[(size_t)((b * 16 + hh) * 64 + dk) * 2048 + s] = hv;
          }
        } else {
          out[(size_t)m * 1024 + n] = v + bias[n];
        }
      }
}

// ----------------------------------------------------------------- V row mean
__global__ void k_vmean(const unsigned short* __restrict__ vt, float* __restrict__ vmean) {
  int row = blockIdx.x * 4 + (threadIdx.x >> 6);
  int lane = threadIdx.x & 63;
  const unsigned short* p = vt + (size_t)row * 2048 + lane * 32;
  float s = 0.f;
#pragma unroll
  for (int j = 0; j < 32; j += 8) {
    us8v v = *(const us8v*)(p + j);
#pragma unroll
    for (int e = 0; e < 8; e++) s += bf2f(v[e]);
  }
#pragma unroll
  for (int m = 1; m < 64; m <<= 1) s += __shfl_xor(s, m);
  if (lane == 0) vmean[row] = s * (1.0f / 2048.0f);
}

// ------------------------------------------------------------ flash attention
// Swapped QK^T: S^T = mfma(K_frag, Q_frag) => lane holds 16 scores for ONE
// q-row (q = c0), keys 16t+4g+r.  Softmax is lane-local + 2 shfl_xor (cross-g).
__global__ __launch_bounds__(256) void k_attn(const unsigned short* __restrict__ qklin,
                                              const unsigned short* __restrict__ vt,
                                              const int* __restrict__ kpm,
                                              const float* __restrict__ vmean,
                                              unsigned short* __restrict__ ctx) {
  __shared__ unsigned short lds_k[2][64 * 64];
  __shared__ unsigned short lds_v[64 * 64];
  __shared__ unsigned short p_lds[4][16 * 64];
  int wg = blockIdx.x;
  int qt = 31 - (wg >> 5), bh = wg & 31;
  int b = bh >> 4, h = bh & 15;
  int tid = threadIdx.x, lane = tid & 63, w = tid >> 6;
  int g = lane >> 4, c0 = lane & 15;
  int q0 = qt * 64 + w * 16;
  unsigned short* pl = p_lds[w];
  int rrel = lane >> 3, gran = lane & 7;

  const unsigned short* ksrc0 = qklin + (size_t)(b * NS) * 2048 + 1024 + h * 64;
  const unsigned short* vsrc0 = vt + (size_t)(bh * 64) * 2048;

  const unsigned short* qbase = qklin + (size_t)(b * NS + q0 + c0) * 2048 + h * 64 + 8 * g;
  s8v qf0 = *(const s8v*)(qbase);
  s8v qf1 = *(const s8v*)(qbase + 32);

  f4v cacc[4];
#pragma unroll
  for (int d = 0; d < 4; d++) cacc[d] = (f4v){0.f, 0.f, 0.f, 0.f};
  float m_s = -1e30f, l_s = 0.f;
  int qrow = q0 + c0;

  // prologue: stage K tile 0
#pragma unroll
  for (int i = 0; i < 2; i++) {
    int r = 16 * w + 8 * i + rrel;
    gload16(ksrc0 + (size_t)r * 2048 + 8 * (gran ^ rrel),
            (void*)(lds_k[0] + (16 * w + 8 * i) * 64));
  }
  __syncthreads();

  int nkt = qt + 1;
  for (int it = 0; it < nkt; ++it) {
    int kb = it * 64;
    int cur = it & 1;
    // ---- stage V(it) (consumed in PV this iter, after the barrier)
#pragma unroll
    for (int i = 0; i < 2; i++) {
      int r = 16 * w + 8 * i + rrel;
      gload16(vsrc0 + (size_t)r * 2048 + kb + 8 * (gran ^ rrel),
              (void*)(lds_v + (16 * w + 8 * i) * 64));
    }
    // ---- stage K(it+1) into the other buffer
    if (it < qt) {
#pragma unroll
      for (int i = 0; i < 2; i++) {
        int r = 16 * w + 8 * i + rrel;
        gload16(ksrc0 + (size_t)(kb + 64 + r) * 2048 + 8 * (gran ^ rrel),
                (void*)(lds_k[cur ^ 1] + (16 * w + 8 * i) * 64));
      }
    }
    // ---- key-padding mask (1 coalesced load + ballot)
    int kp = kpm[b * NS + kb + lane];
    uint64_t padmask = __ballot(kp != 0);
    // ---- scores: S^T tiles, lane holds q=c0, keys 16t+4g+r
    f4v sacc[4];
#pragma unroll
    for (int t = 0; t < 4; t++) {
      int row = 16 * t + c0;
      s8v kf0 = *(const s8v*)(lds_k[cur] + row * 64 + 8 * (g ^ (c0 & 7)));
      s8v kf1 = *(const s8v*)(lds_k[cur] + row * 64 + 8 * ((4 + g) ^ (c0 & 7)));
      f4v z = (f4v){0.f, 0.f, 0.f, 0.f};
      z = __builtin_amdgcn_mfma_f32_16x16x32_bf16(kf0, qf0, z, 0, 0, 0);
      z = __builtin_amdgcn_mfma_f32_16x16x32_bf16(kf1, qf1, z, 0, 0, 0);
      sacc[t] = z;
    }
    // ---- validity mask: causal threshold + padding
    int thr = qrow - kb;
    uint64_t cmask = (thr >= 63) ? ~0ull : ((2ull << thr) - 1ull);
    uint64_t valid = cmask & ~padmask;
    float p[4][4];
    float mx = -1e30f;
#pragma unroll
    for (int t = 0; t < 4; t++) {
      uint32_t nib = (uint32_t)(valid >> (16 * t + 4 * g)) & 0xFu;
#pragma unroll
      for (int r = 0; r < 4; r++) {
        float s = sacc[t][r];
        s = ((nib >> r) & 1u) ? s : -1e30f;
        p[t][r] = s;
      }
      mx = fmaxf(mx, fmaxf(fmaxf(p[t][0], p[t][1]), fmaxf(p[t][2], p[t][3])));
    }
    mx = fmaxf(mx, __shfl_xor(mx, 16));
    mx = fmaxf(mx, __shfl_xor(mx, 32));
    float mnew = fmaxf(m_s, mx);
    float a = __expf(m_s - mnew);
    float rs = 0.f;
#pragma unroll
    for (int t = 0; t < 4; t++)
#pragma unroll
      for (int r = 0; r < 4; r++) {
        float e = __expf(p[t][r] - mnew);
        p[t][r] = e;
        rs += e;
      }
    rs += __shfl_xor(rs, 16);
    rs += __shfl_xor(rs, 32);
    rs = (mnew > -1e29f) ? rs : 0.f;
    l_s = l_s * a + rs;
    m_s = mnew;
    // ---- redistribute rescale factor to cacc rows (q = 4g+r at this lane)
    {
      int ybase = 20 * g;
#pragma unroll
      for (int r = 0; r < 4; r++) {
        float ar = __shfl(a, ybase + r);
#pragma unroll
        for (int d = 0; d < 4; d++) cacc[d][r] *= ar;
      }
    }
    // ---- pack P -> LDS: row q=c0, cols 16t+4g+{0..3} = one b64 per t
#pragma unroll
    for (int t = 0; t < 4; t++) {
      u2v pk;
      pk[0] = cvtpk(p[t][0], p[t][1]);
      pk[1] = cvtpk(p[t][2], p[t][3]);
      int gr = (2 * t + (g >> 1)) ^ (c0 & 7);
      *(u2v*)((char*)pl + c0 * 128 + gr * 16 + 8 * (g & 1)) = pk;
    }
    __syncthreads();
    // ---- PV from lds_v
#pragma unroll
    for (int c = 0; c < 2; c++) {
      int off = c0 * 128 + 16 * g + 64 * c;
      off ^= (c0 & 7) << 4;
      s8v pf = *(const s8v*)((const char*)pl + off);
#pragma unroll
      for (int d = 0; d < 4; d++) {
        int row = 16 * d + c0;
        s8v vf = *(const s8v*)(lds_v + row * 64 + 8 * ((4 * c + g) ^ (c0 & 7)));
        cacc[d] = __builtin_amdgcn_mfma_f32_16x16x32_bf16(pf, vf, cacc[d], 0, 0, 0);
      }
    }
    __syncthreads();
  }
  // ---- epilogue
  float lq[4];
  {
    int ybase = 20 * g;
#pragma unroll
    for (int r = 0; r < 4; r++) lq[r] = __shfl(l_s, ybase + r);
  }
#pragma unroll
  for (int d = 0; d < 4; d++)
#pragma unroll
    for (int r = 0; r < 4; r++) {
      int q = q0 + 4 * g + r;
      float l = lq[r];
      float v = (l > 0.f) ? cacc[d][r] / l : vmean[bh * 64 + 16 * d + c0];
      ctx[(size_t)(b * NS + q) * ND + h * 64 + 16 * d + c0] = f2bf(v);
    }
}

// ----------------------------------------------------------------------------
extern "C" void kernel_launch(void* const* d_in, const int* in_sizes, int n_in,
                              void* d_out, int out_size, void* d_ws, size_t ws_size,
                              hipStream_t stream) {
  const float* x  = (const float*)d_in[0];
  const int* kpm  = (const int*)d_in[2];
  const float* Wq = (const float*)d_in[3];
  const float* Wk = (const float*)d_in[4];
  const float* Wv = (const float*)d_in[5];
  const float* Wo = (const float*)d_in[6];
  const float* bo = (const float*)d_in[7];

  char* ws = (char*)d_ws;
  unsigned short* xbf   = (unsigned short*)(ws);
  unsigned short* wtqkv = (unsigned short*)(ws + 8u * 1024 * 1024);
  unsigned short* wto   = (unsigned short*)(ws + 14u * 1024 * 1024);
  unsigned short* vt    = (unsigned short*)(ws + 16u * 1024 * 1024);
  float* vmean          = (float*)(ws + 24u * 1024 * 1024);
  unsigned short* ctx   = xbf;
  unsigned short* qklin = (unsigned short*)d_out;

  k_convert_x<<<4096, 256, 0, stream>>>(x, xbf);
  k_transpose_w<<<1024, 256, 0, stream>>>(Wq, Wk, Wv, Wo, wtqkv, wto);
  k_gemm<0><<<768, 256, 0, stream>>>(xbf, wtqkv, qklin, vt, nullptr, nullptr, 24);
  k_vmean<<<512, 256, 0, stream>>>(vt, vmean);
  k_attn<<<1024, 256, 0, stream>>>(qklin, vt, kpm, vmean, ctx);
  k_gemm<1><<<256, 256, 0, stream>>>(ctx, wto, nullptr, nullptr, bo, (float*)d_out, 8);
}

// Round 8
// 140.759 us; speedup vs baseline: 1.0806x; 1.0806x over previous
//
#include <hip/hip_runtime.h>
#include <stdint.h>

#define NB 2
#define NS 2048
#define ND 1024
#define NH 16
#define NDK 64

typedef __attribute__((ext_vector_type(8))) short s8v;
typedef __attribute__((ext_vector_type(4))) float f4v;
typedef __attribute__((ext_vector_type(4))) unsigned short us4v;
typedef __attribute__((ext_vector_type(8))) unsigned short us8v;
typedef __attribute__((ext_vector_type(2))) uint32_t u2v;

__device__ __forceinline__ unsigned short f2bf(float f) {
  uint32_t u = __builtin_bit_cast(uint32_t, f);
  u = (u + 0x7fffu + ((u >> 16) & 1u)) >> 16;
  return (unsigned short)u;
}
__device__ __forceinline__ float bf2f(unsigned short h) {
  uint32_t u = ((uint32_t)h) << 16;
  return __builtin_bit_cast(float, u);
}
// packed f32x2 -> bf16x2 (lo -> bits[15:0]), RNE
__device__ __forceinline__ uint32_t cvtpk(float lo, float hi) {
  uint32_t r;
  asm("v_cvt_pk_bf16_f32 %0, %1, %2" : "=v"(r) : "v"(lo), "v"(hi));
  return r;
}

__device__ __forceinline__ void gload16(const void* g, void* l) {
  __builtin_amdgcn_global_load_lds(
      (const __attribute__((address_space(1))) void*)g,
      (__attribute__((address_space(3))) void*)l, 16, 0, 0);
}

// ---------------------------------------------------------------- convert x
__global__ void k_convert_x(const float* __restrict__ x, unsigned short* __restrict__ xbf) {
  int i = (blockIdx.x * 256 + threadIdx.x) * 4;
  float4 v = *(const float4*)(x + i);
  us4v o;
  o[0] = f2bf(v.x); o[1] = f2bf(v.y); o[2] = f2bf(v.z); o[3] = f2bf(v.w);
  *(us4v*)(xbf + i) = o;
}

// ------------------------------------------------- transpose+convert weights
__global__ void k_transpose_w(const float* __restrict__ Wq, const float* __restrict__ Wk,
                              const float* __restrict__ Wv, const float* __restrict__ Wo,
                              unsigned short* __restrict__ wt_qkv, unsigned short* __restrict__ wt_o) {
  __shared__ float tls[64][65];
  int bid = blockIdx.x;
  int mat = bid >> 8;
  int tile = bid & 255;
  int tk = tile >> 4, tn = tile & 15;
  const float* W = (mat == 0) ? Wq : (mat == 1) ? Wk : (mat == 2) ? Wv : Wo;
  int t = threadIdx.x;
  int lr = t >> 2;
  int lc0 = (t & 3) * 16;
  const float* src = W + (size_t)(tk * 64 + lr) * 1024 + tn * 64 + lc0;
#pragma unroll
  for (int j = 0; j < 16; j += 4) {
    float4 v = *(const float4*)(src + j);
    tls[lr][lc0 + j + 0] = v.x; tls[lr][lc0 + j + 1] = v.y;
    tls[lr][lc0 + j + 2] = v.z; tls[lr][lc0 + j + 3] = v.w;
  }
  __syncthreads();
  float scale = (mat == 0) ? 0.125f : 1.0f;
  int nr = t >> 2, kc0 = (t & 3) * 16;
  unsigned short* dst = ((mat < 3) ? (wt_qkv + (size_t)(mat * 1024 + tn * 64 + nr) * 1024)
                                   : (wt_o + (size_t)(tn * 64 + nr) * 1024)) + tk * 64 + kc0;
  us8v o0, o1;
#pragma unroll
  for (int j = 0; j < 8; j++) o0[j] = f2bf(tls[kc0 + j][nr] * scale);
#pragma unroll
  for (int j = 0; j < 8; j++) o1[j] = f2bf(tls[kc0 + 8 + j][nr] * scale);
  *(us8v*)(dst) = o0;
  *(us8v*)(dst + 8) = o1;
}

// ----------------------------------------------------------------- bf16 GEMM
// R6 2-phase structure (proven 60us): STAGE(kt+1) before compute(kt), one
// __syncthreads per iter (drain lands after compute).  64KB LDS -> 2 WG/CU,
// cross-WG overlap does the residual hiding.  R7's L2 chunk indexing kept:
// m cycles fastest within an XCD chunk (concurrent WGs share B columns).
template <int MODE>
__global__ __launch_bounds__(256) void k_gemm(const unsigned short* __restrict__ A,
                                              const unsigned short* __restrict__ Bt,
                                              unsigned short* __restrict__ qklin,
                                              unsigned short* __restrict__ vt,
                                              const float* __restrict__ bias,
                                              float* __restrict__ out) {
  __shared__ unsigned short lds_a[2][128 * 64];
  __shared__ unsigned short lds_b[2][128 * 64];
  const int K = 1024;
  const int NT = K / 64;
  int bid = blockIdx.x;
  int xcd = bid & 7, local = bid >> 3;
  int m0 = (xcd * 4 + (local & 3)) * 128;
  int n0 = (local >> 2) * 128;
  int tid = threadIdx.x, lane = tid & 63, w = tid >> 6;
  int wm = w >> 1, wn = w & 1;
  int g = lane >> 4, c0 = lane & 15;
  int rrel = lane >> 3;
  int gran = lane & 7;
  f4v acc[4][4];
#pragma unroll
  for (int mi = 0; mi < 4; mi++)
#pragma unroll
    for (int ni = 0; ni < 4; ni++) acc[mi][ni] = (f4v){0.f, 0.f, 0.f, 0.f};

#define STAGE(kt_, buf_)                                                        \
  do {                                                                          \
    int koff = (kt_)*64;                                                        \
    _Pragma("unroll") for (int i = 0; i < 4; i++) {                             \
      int r = 32 * w + 8 * i + rrel;                                            \
      gload16(A + (size_t)(m0 + r) * K + koff + 8 * (gran ^ rrel),              \
              (void*)(lds_a[buf_] + (32 * w + 8 * i) * 64));                    \
      gload16(Bt + (size_t)(n0 + r) * K + koff + 8 * (gran ^ rrel),             \
              (void*)(lds_b[buf_] + (32 * w + 8 * i) * 64));                    \
    }                                                                           \
  } while (0)

  STAGE(0, 0);
  __syncthreads();

  for (int kt = 0; kt < NT; ++kt) {
    int cur = kt & 1;
    if (kt + 1 < NT) STAGE(kt + 1, cur ^ 1);
    // ---- compute from buf[cur]
#pragma unroll
    for (int c = 0; c < 2; c++) {
      s8v af[4], bfr[4];
#pragma unroll
      for (int mi = 0; mi < 4; mi++) {
        int row = 64 * wm + 16 * mi + c0;
        af[mi] = *(const s8v*)(lds_a[cur] + row * 64 + 8 * ((g + 4 * c) ^ (c0 & 7)));
      }
#pragma unroll
      for (int ni = 0; ni < 4; ni++) {
        int row = 64 * wn + 16 * ni + c0;
        bfr[ni] = *(const s8v*)(lds_b[cur] + row * 64 + 8 * ((g + 4 * c) ^ (c0 & 7)));
      }
#pragma unroll
      for (int mi = 0; mi < 4; mi++)
#pragma unroll
        for (int ni = 0; ni < 4; ni++)
          acc[mi][ni] = __builtin_amdgcn_mfma_f32_16x16x32_bf16(af[mi], bfr[ni], acc[mi][ni], 0, 0, 0);
    }
    __syncthreads();
  }
#undef STAGE

#pragma unroll
  for (int mi = 0; mi < 4; mi++)
#pragma unroll
    for (int ni = 0; ni < 4; ni++)
#pragma unroll
      for (int r = 0; r < 4; r++) {
        int m = m0 + 64 * wm + 16 * mi + 4 * g + r;
        int n = n0 + 64 * wn + 16 * ni + c0;
        float v = acc[mi][ni][r];
        if (MODE == 0) {
          unsigned short hv = f2bf(v);
          if (n < 2048) {
            qklin[(size_t)m * 2048 + n] = hv;
          } else {
            int b = m >> 11, s = m & 2047;
            int hh = (n - 2048) >> 6, dk = n & 63;
            vt[(size_t)((b * 16 + hh) * 64 + dk) * 2048 + s] = hv;
          }
        } else {
          out[(size_t)m * 1024 + n] = v + bias[n];
        }
      }
}

// ----------------------------------------------------------------- V row mean
__global__ void k_vmean(const unsigned short* __restrict__ vt, float* __restrict__ vmean) {
  int row = blockIdx.x * 4 + (threadIdx.x >> 6);
  int lane = threadIdx.x & 63;
  const unsigned short* p = vt + (size_t)row * 2048 + lane * 32;
  float s = 0.f;
#pragma unroll
  for (int j = 0; j < 32; j += 8) {
    us8v v = *(const us8v*)(p + j);
#pragma unroll
    for (int e = 0; e < 8; e++) s += bf2f(v[e]);
  }
#pragma unroll
  for (int m = 1; m < 64; m <<= 1) s += __shfl_xor(s, m);
  if (lane == 0) vmean[row] = s * (1.0f / 2048.0f);
}

// ------------------------------------------------------------ flash attention
// Swapped QK^T (lane owns q-row c0).  NEW: K and V both double-buffered;
// S(it+1)={K,V} staged at iter top + kpm(it+1) prefetch as the 5th VMEM op;
// counted vmcnt(5) retires exactly S(it)+kp(it) while S(it+1) stays in flight
// across both barriers (T4) -- no vmcnt(0) drain in the loop.  Staging latency
// hides under a full iteration.  2 raw s_barriers/iter: (1) after vmcnt(5),
// publishes S(it); (2) after PV, seals reads of buf[cur] before next staging.
// P_lds is per-wave: lgkmcnt(0)+sched_barrier(0) only (rule #18).
__global__ __launch_bounds__(256) void k_attn(const unsigned short* __restrict__ qklin,
                                              const unsigned short* __restrict__ vt,
                                              const int* __restrict__ kpm,
                                              const float* __restrict__ vmean,
                                              unsigned short* __restrict__ ctx) {
  __shared__ unsigned short lds_k[2][64 * 64];
  __shared__ unsigned short lds_v[2][64 * 64];
  __shared__ unsigned short p_lds[4][16 * 64];
  int wg = blockIdx.x;
  int qt = 31 - (wg >> 5), bh = wg & 31;
  int b = bh >> 4, h = bh & 15;
  int tid = threadIdx.x, lane = tid & 63, w = tid >> 6;
  int g = lane >> 4, c0 = lane & 15;
  int q0 = qt * 64 + w * 16;
  unsigned short* pl = p_lds[w];
  int rrel = lane >> 3, gran = lane & 7;

  const unsigned short* ksrc0 = qklin + (size_t)(b * NS) * 2048 + 1024 + h * 64;
  const unsigned short* vsrc0 = vt + (size_t)(bh * 64) * 2048;

  const unsigned short* qbase = qklin + (size_t)(b * NS + q0 + c0) * 2048 + h * 64 + 8 * g;
  s8v qf0 = *(const s8v*)(qbase);
  s8v qf1 = *(const s8v*)(qbase + 32);

  f4v cacc[4];
#pragma unroll
  for (int d = 0; d < 4; d++) cacc[d] = (f4v){0.f, 0.f, 0.f, 0.f};
  float m_s = -1e30f, l_s = 0.f;
  int qrow = q0 + c0;

#define STAGEKV(it_, buf_)                                                      \
  do {                                                                          \
    int kb_ = (it_)*64;                                                         \
    _Pragma("unroll") for (int i = 0; i < 2; i++) {                             \
      int r = 16 * w + 8 * i + rrel;                                            \
      gload16(ksrc0 + (size_t)(kb_ + r) * 2048 + 8 * (gran ^ rrel),             \
              (void*)(lds_k[buf_] + (16 * w + 8 * i) * 64));                    \
      gload16(vsrc0 + (size_t)r * 2048 + kb_ + 8 * (gran ^ rrel),               \
              (void*)(lds_v[buf_] + (16 * w + 8 * i) * 64));                    \
    }                                                                           \
  } while (0)

  // prologue: stage tile 0 (4 loads) + kp(0) prefetch (5th VMEM)
  STAGEKV(0, 0);
  int kp_cur = kpm[b * NS + lane];

  int nkt = qt + 1;
  for (int it = 0; it < nkt; ++it) {
    int kb = it * 64;
    int cur = it & 1;
    int kp_next = 0;
    if (it + 1 < nkt) {
      STAGEKV(it + 1, cur ^ 1);                    // 4 loads
      kp_next = kpm[b * NS + (it + 1) * 64 + lane];  // 5th
      asm volatile("s_waitcnt vmcnt(5)" ::: "memory");  // retire S(it)+kp(it)
    } else {
      asm volatile("s_waitcnt vmcnt(0)" ::: "memory");
    }
    __builtin_amdgcn_s_barrier();                  // publish S(it) block-wide
    __builtin_amdgcn_sched_barrier(0);
    // ---- key-padding mask (kp_cur retired by the vmcnt above)
    uint64_t padmask = __ballot(kp_cur != 0);
    // ---- scores: S^T tiles, lane holds q=c0, keys 16t+4g+r
    f4v sacc[4];
#pragma unroll
    for (int t = 0; t < 4; t++) {
      int row = 16 * t + c0;
      s8v kf0 = *(const s8v*)(lds_k[cur] + row * 64 + 8 * (g ^ (c0 & 7)));
      s8v kf1 = *(const s8v*)(lds_k[cur] + row * 64 + 8 * ((4 + g) ^ (c0 & 7)));
      f4v z = (f4v){0.f, 0.f, 0.f, 0.f};
      z = __builtin_amdgcn_mfma_f32_16x16x32_bf16(kf0, qf0, z, 0, 0, 0);
      z = __builtin_amdgcn_mfma_f32_16x16x32_bf16(kf1, qf1, z, 0, 0, 0);
      sacc[t] = z;
    }
    // ---- validity mask: causal threshold + padding
    int thr = qrow - kb;
    uint64_t cmask = (thr >= 63) ? ~0ull : ((2ull << thr) - 1ull);
    uint64_t valid = cmask & ~padmask;
    float p[4][4];
    float mx = -1e30f;
#pragma unroll
    for (int t = 0; t < 4; t++) {
      uint32_t nib = (uint32_t)(valid >> (16 * t + 4 * g)) & 0xFu;
#pragma unroll
      for (int r = 0; r < 4; r++) {
        float s = sacc[t][r];
        s = ((nib >> r) & 1u) ? s : -1e30f;
        p[t][r] = s;
      }
      mx = fmaxf(mx, fmaxf(fmaxf(p[t][0], p[t][1]), fmaxf(p[t][2], p[t][3])));
    }
    mx = fmaxf(mx, __shfl_xor(mx, 16));
    mx = fmaxf(mx, __shfl_xor(mx, 32));
    float mnew = fmaxf(m_s, mx);
    float a = __expf(m_s - mnew);
    float rs = 0.f;
#pragma unroll
    for (int t = 0; t < 4; t++)
#pragma unroll
      for (int r = 0; r < 4; r++) {
        float e = __expf(p[t][r] - mnew);
        p[t][r] = e;
        rs += e;
      }
    rs += __shfl_xor(rs, 16);
    rs += __shfl_xor(rs, 32);
    rs = (mnew > -1e29f) ? rs : 0.f;
    l_s = l_s * a + rs;
    m_s = mnew;
    // ---- redistribute rescale factor to cacc rows (q = 4g+r at this lane)
    {
      int ybase = 20 * g;
#pragma unroll
      for (int r = 0; r < 4; r++) {
        float ar = __shfl(a, ybase + r);
#pragma unroll
        for (int d = 0; d < 4; d++) cacc[d][r] *= ar;
      }
    }
    // ---- pack P -> per-wave LDS: row q=c0, cols 16t+4g+{0..3} (one b64 per t)
#pragma unroll
    for (int t = 0; t < 4; t++) {
      u2v pk;
      pk[0] = cvtpk(p[t][0], p[t][1]);
      pk[1] = cvtpk(p[t][2], p[t][3]);
      int gr = (2 * t + (g >> 1)) ^ (c0 & 7);
      *(u2v*)((char*)pl + c0 * 128 + gr * 16 + 8 * (g & 1)) = pk;
    }
    asm volatile("s_waitcnt lgkmcnt(0)" ::: "memory");
    __builtin_amdgcn_sched_barrier(0);
    // ---- PV from lds_v[cur]
#pragma unroll
    for (int c = 0; c < 2; c++) {
      int off = c0 * 128 + 16 * g + 64 * c;
      off ^= (c0 & 7) << 4;
      s8v pf = *(const s8v*)((const char*)pl + off);
#pragma unroll
      for (int d = 0; d < 4; d++) {
        int row = 16 * d + c0;
        s8v vf = *(const s8v*)(lds_v[cur] + row * 64 + 8 * ((4 * c + g) ^ (c0 & 7)));
        cacc[d] = __builtin_amdgcn_mfma_f32_16x16x32_bf16(pf, vf, cacc[d], 0, 0, 0);
      }
    }
    __builtin_amdgcn_s_barrier();   // seal reads of buf[cur] before next staging
    __builtin_amdgcn_sched_barrier(0);
    kp_cur = kp_next;
  }
#undef STAGEKV
  // ---- epilogue
  float lq[4];
  {
    int ybase = 20 * g;
#pragma unroll
    for (int r = 0; r < 4; r++) lq[r] = __shfl(l_s, ybase + r);
  }
#pragma unroll
  for (int d = 0; d < 4; d++)
#pragma unroll
    for (int r = 0; r < 4; r++) {
      int q = q0 + 4 * g + r;
      float l = lq[r];
      float v = (l > 0.f) ? cacc[d][r] / l : vmean[bh * 64 + 16 * d + c0];
      ctx[(size_t)(b * NS + q) * ND + h * 64 + 16 * d + c0] = f2bf(v);
    }
}

// ----------------------------------------------------------------------------
extern "C" void kernel_launch(void* const* d_in, const int* in_sizes, int n_in,
                              void* d_out, int out_size, void* d_ws, size_t ws_size,
                              hipStream_t stream) {
  const float* x  = (const float*)d_in[0];
  const int* kpm  = (const int*)d_in[2];
  const float* Wq = (const float*)d_in[3];
  const float* Wk = (const float*)d_in[4];
  const float* Wv = (const float*)d_in[5];
  const float* Wo = (const float*)d_in[6];
  const float* bo = (const float*)d_in[7];

  char* ws = (char*)d_ws;
  unsigned short* xbf   = (unsigned short*)(ws);
  unsigned short* wtqkv = (unsigned short*)(ws + 8u * 1024 * 1024);
  unsigned short* wto   = (unsigned short*)(ws + 14u * 1024 * 1024);
  unsigned short* vt    = (unsigned short*)(ws + 16u * 1024 * 1024);
  float* vmean          = (float*)(ws + 24u * 1024 * 1024);
  unsigned short* ctx   = xbf;
  unsigned short* qklin = (unsigned short*)d_out;

  k_convert_x<<<4096, 256, 0, stream>>>(x, xbf);
  k_transpose_w<<<1024, 256, 0, stream>>>(Wq, Wk, Wv, Wo, wtqkv, wto);
  k_gemm<0><<<768, 256, 0, stream>>>(xbf, wtqkv, qklin, vt, nullptr, nullptr);
  k_vmean<<<512, 256, 0, stream>>>(vt, vmean);
  k_attn<<<1024, 256, 0, stream>>>(qklin, vt, kpm, vmean, ctx);
  k_gemm<1><<<256, 256, 0, stream>>>(ctx, wto, nullptr, nullptr, bo, (float*)d_out);
}